// Round 2
// baseline (3938.559 us; speedup 1.0000x reference)
//
#include <hip/hip_runtime.h>
#include <cstdint>
#include <cstddef>

// ---------------------------------------------------------------------------
// Sizes (fixed by the problem)
// ---------------------------------------------------------------------------
#define DIM    1024
#define NH     16
#define HD     64
#define DI     4
#define CHUNK_ 16
#define SEQ    4096
#define BATCH  4
#define NROWS  (BATCH * SEQ)       // 16384
#define NCHUNK (SEQ / CHUNK_)      // 256
#define SEG    64                  // conv in-place segment length (rows)
#define NSEG   (SEQ / SEG)         // 64

// ---------------------------------------------------------------------------
// GEMM (NT): C[m][n] = sum_k A[m*K + k] * B[n*K + k]
// 128x128 tile, BK=16, 256 threads, 8x8 micro-tile per thread. fp32.
// ---------------------------------------------------------------------------
__global__ __launch_bounds__(256)
void gemm_nt_f32(const float* __restrict__ A, const float* __restrict__ B,
                 float* __restrict__ C, int K, int ldc)
{
    __shared__ float As[16][132];
    __shared__ float Bs[16][132];

    const int tid = threadIdx.x;
    const int tx  = tid & 15;
    const int ty  = tid >> 4;
    const int m0  = blockIdx.y * 128;
    const int n0  = blockIdx.x * 128;
    const int lrow = tid >> 2;          // 0..63
    const int lcol = (tid & 3) << 2;    // 0,4,8,12

    float acc[8][8];
#pragma unroll
    for (int i = 0; i < 8; ++i)
#pragma unroll
        for (int j = 0; j < 8; ++j) acc[i][j] = 0.f;

    for (int kt = 0; kt < K; kt += 16) {
        float4 a0 = *(const float4*)(A + (size_t)(m0 + lrow)      * K + kt + lcol);
        float4 a1 = *(const float4*)(A + (size_t)(m0 + lrow + 64) * K + kt + lcol);
        float4 b0 = *(const float4*)(B + (size_t)(n0 + lrow)      * K + kt + lcol);
        float4 b1 = *(const float4*)(B + (size_t)(n0 + lrow + 64) * K + kt + lcol);

        __syncthreads();
        As[lcol + 0][lrow] = a0.x; As[lcol + 1][lrow] = a0.y;
        As[lcol + 2][lrow] = a0.z; As[lcol + 3][lrow] = a0.w;
        As[lcol + 0][lrow + 64] = a1.x; As[lcol + 1][lrow + 64] = a1.y;
        As[lcol + 2][lrow + 64] = a1.z; As[lcol + 3][lrow + 64] = a1.w;
        Bs[lcol + 0][lrow] = b0.x; Bs[lcol + 1][lrow] = b0.y;
        Bs[lcol + 2][lrow] = b0.z; Bs[lcol + 3][lrow] = b0.w;
        Bs[lcol + 0][lrow + 64] = b1.x; Bs[lcol + 1][lrow + 64] = b1.y;
        Bs[lcol + 2][lrow + 64] = b1.z; Bs[lcol + 3][lrow + 64] = b1.w;
        __syncthreads();

#pragma unroll
        for (int kk = 0; kk < 16; ++kk) {
            float4 av0 = *(const float4*)&As[kk][ty * 8];
            float4 av1 = *(const float4*)&As[kk][ty * 8 + 4];
            float4 bv0 = *(const float4*)&Bs[kk][tx * 8];
            float4 bv1 = *(const float4*)&Bs[kk][tx * 8 + 4];
            float a[8] = {av0.x, av0.y, av0.z, av0.w, av1.x, av1.y, av1.z, av1.w};
            float b[8] = {bv0.x, bv0.y, bv0.z, bv0.w, bv1.x, bv1.y, bv1.z, bv1.w};
#pragma unroll
            for (int i = 0; i < 8; ++i)
#pragma unroll
                for (int j = 0; j < 8; ++j)
                    acc[i][j] = fmaf(a[i], b[j], acc[i][j]);
        }
    }

#pragma unroll
    for (int i = 0; i < 8; ++i) {
        size_t row = (size_t)(m0 + ty * 8 + i);
        float4 c0, c1;
        c0.x = acc[i][0]; c0.y = acc[i][1]; c0.z = acc[i][2]; c0.w = acc[i][3];
        c1.x = acc[i][4]; c1.y = acc[i][5]; c1.z = acc[i][6]; c1.w = acc[i][7];
        *(float4*)(C + row * ldc + n0 + tx * 8)     = c0;
        *(float4*)(C + row * ldc + n0 + tx * 8 + 4) = c1;
    }
}

// ---------------------------------------------------------------------------
// lr kernel: LR[r][o] = softplus(hs[r,:] . Wlr[o,:] + 1e-3),  o in [0,32)
// ---------------------------------------------------------------------------
__global__ __launch_bounds__(256)
void lr_kernel(const float* __restrict__ hs, const float* __restrict__ Wlr,
               float* __restrict__ LR)
{
    __shared__ float row[DIM];
    const int r = blockIdx.x;
    const int t = threadIdx.x;
    *(float4*)&row[t * 4] = *(const float4*)&hs[(size_t)r * DIM + t * 4];
    __syncthreads();

    const int o = t >> 3;       // 0..31
    const int p = t & 7;        // 0..7
    const float* w = Wlr + (size_t)o * DIM + p * 128;
    const float* x = row + p * 128;
    float acc = 0.f;
#pragma unroll
    for (int i = 0; i < 32; ++i) {
        float4 xv = *(const float4*)(x + i * 4);
        float4 wv = *(const float4*)(w + i * 4);
        acc += xv.x * wv.x + xv.y * wv.y + xv.z * wv.z + xv.w * wv.w;
    }
    acc += __shfl_xor(acc, 1);
    acc += __shfl_xor(acc, 2);
    acc += __shfl_xor(acc, 4);
    if (p == 0) {
        float xx = acc + 0.001f;
        LR[(size_t)r * 32 + o] = (xx > 20.f) ? xx : log1pf(expf(xx));
    }
}

// ---------------------------------------------------------------------------
// halo save: before in-place conv, save the 3 tail rows of each 64-row
// segment (they are the history for the NEXT segment, which another wave
// will overwrite concurrently). halo[((t*4+b)*NSEG+s)*3 + j][c] = x row
// (b*SEQ + s*SEG - 3 + j), for s in 1..NSEG-1.
// One block (256 thr) per saved row (float4 per thread).
// ---------------------------------------------------------------------------
__global__ __launch_bounds__(256)
void halo_save(const float* __restrict__ Q, const float* __restrict__ K,
               const float* __restrict__ V, float* __restrict__ HALO)
{
    int idx = blockIdx.x;                    // 3 * 4 * (NSEG-1) * 3 = 2268
    int tn  = idx / (BATCH * (NSEG - 1) * 3);
    int rem = idx - tn * (BATCH * (NSEG - 1) * 3);
    int b   = rem / ((NSEG - 1) * 3);
    int rem2= rem - b * ((NSEG - 1) * 3);
    int s   = rem2 / 3 + 1;                  // 1..NSEG-1
    int j   = rem2 - (s - 1) * 3;            // 0..2

    const float* buf = (tn == 0) ? Q : ((tn == 1) ? K : V);
    size_t src = ((size_t)(b * SEQ + s * SEG - 3 + j)) * DIM + threadIdx.x * 4;
    size_t dst = ((size_t)((tn * BATCH + b) * NSEG + s) * 3 + j) * DIM + threadIdx.x * 4;
    *(float4*)&HALO[dst] = *(const float4*)&buf[src];
}

// ---------------------------------------------------------------------------
// conv in-place: causal depthwise conv (KSZ=4) + residual + silu; l2norm q,k.
// One wave per (tensor, b, h, segment). Each lane owns one channel; scans the
// 64 rows serially, history in registers, writes in place.
// ---------------------------------------------------------------------------
__global__ __launch_bounds__(256)
void conv_inplace(float* __restrict__ Q, float* __restrict__ K,
                  float* __restrict__ V, const float* __restrict__ HALO,
                  const float* __restrict__ cq, const float* __restrict__ ck,
                  const float* __restrict__ cv)
{
    const int wid  = (blockIdx.x << 2) + (threadIdx.x >> 6);   // 0..12287
    const int lane = threadIdx.x & 63;
    const int tn   = wid >> 12;              // 0..2
    const int rem  = wid & 4095;
    const int b    = rem >> 10;
    const int rem2 = rem & 1023;
    const int h    = rem2 >> 6;
    const int s    = rem2 & 63;
    const int c    = (h << 6) + lane;

    float* buf = (tn == 0) ? Q : ((tn == 1) ? K : V);
    const float* cw = (tn == 0) ? cq : ((tn == 1) ? ck : cv);
    float4 w4 = *(const float4*)(cw + (c << 2));   // w[c][0..3]

    float xm3 = 0.f, xm2 = 0.f, xm1 = 0.f;
    if (s > 0) {
        size_t hb = ((size_t)((tn * BATCH + b) * NSEG + s) * 3) * DIM + c;
        xm3 = HALO[hb];
        xm2 = HALO[hb + DIM];
        xm1 = HALO[hb + 2 * DIM];
    }

    size_t base = ((size_t)(b * SEQ + s * SEG)) * DIM + c;
    float x_next = buf[base];
#pragma unroll 4
    for (int i = 0; i < SEG; ++i) {
        float x = x_next;
        if (i < SEG - 1) x_next = buf[base + (size_t)(i + 1) * DIM];
        float y = x_next;  // placeholder to keep compiler from sinking load
        y = xm3 * w4.x + xm2 * w4.y + xm1 * w4.z + x * w4.w + x;
        y = y / (1.f + expf(-y));              // silu
        if (tn < 2) {                          // l2norm over the head's 64 ch
            float n2 = y * y;
#pragma unroll
            for (int m = 1; m < 64; m <<= 1) n2 += __shfl_xor(n2, m);
            y *= rsqrtf(n2);
        }
        buf[base + (size_t)i * DIM] = y;
        xm3 = xm2; xm2 = xm1; xm1 = x;
    }
}

// ---------------------------------------------------------------------------
// Scan kernel: one block (256 threads) per (b,h) chain; 256 sequential chunks.
// All fp32, small matrices in padded LDS. LayerNorm+gate fused at o-write.
// OB aliases QP (read chunk's q before overwrite; barrier-ordered).
// gate lives in d_out with row stride DIM.
// ---------------------------------------------------------------------------
__global__ __launch_bounds__(256)
void scan_kernel(const float* QP, const float* __restrict__ KP,
                 const float* __restrict__ VP, const float* __restrict__ LRb,
                 const float* __restrict__ GATE,
                 const float* __restrict__ Wi0, const float* __restrict__ Wo0,
                 const float* __restrict__ lng, const float* __restrict__ lnb,
                 float* OB)
{
    const int bh = blockIdx.x;
    const int b  = bh >> 4;
    const int h  = bh & 15;
    const int t  = threadIdx.x;

    __shared__ float sQ[16][68], sK[16][68], sV[16][68];
    __shared__ float Wi[4][68],  Wo_[4][68];
    __shared__ float kh[16][8],  qh[16][8];
    __shared__ float skq[2][16][4];
    __shared__ float qkS[16][16];
    __shared__ float sAtt[2][4][16], pAtt[2][4][16];
    __shared__ float lrb[16][2];

    {   // init per-(b,h) state: W_in/W_out (1, DI, H, HD)
        int D = t >> 6, d = t & 63;
        Wi[D][d]  = Wi0[((size_t)D * NH + h) * HD + d];
        Wo_[D][d] = Wo0[((size_t)D * NH + h) * HD + d];
    }
    const int d0q = (t & 15) * 4;
    float4 lng4 = *(const float4*)&lng[d0q];
    float4 lnb4 = *(const float4*)&lnb[d0q];
    __syncthreads();

    const int rowb = b * SEQ;

    for (int c = 0; c < NCHUNK; ++c) {
        const int rb = rowb + c * CHUNK_;

        // ---- stage chunk ----
        {
            int l = t >> 4, d0 = (t & 15) * 4;
            size_t g = (size_t)(rb + l) * DIM + h * 64 + d0;
            *(float4*)&sQ[l][d0] = *(const float4*)&QP[g];
            *(float4*)&sK[l][d0] = *(const float4*)&KP[g];
            *(float4*)&sV[l][d0] = *(const float4*)&VP[g];
        }
        if (t < 32) {
            int l = t >> 1, j = t & 1;
            lrb[l][j] = LRb[(size_t)(rb + l) * 32 + h * 2 + j];
        }
        __syncthreads();
        const float lr_in  = lrb[0][0];
        const float lr_out = lrb[0][1];

        // ---- logits: s = {k,q}_t . W_in^T  (128 outputs, 2 thr each) ----
        {
            int u = t >> 1, h2 = t & 1;
            int isq = u >> 6;
            int rem = u & 63;
            int l = rem >> 2, D = rem & 3;
            const float* xrow = isq ? &sQ[l][0] : &sK[l][0];
            const float* wrow = &Wi[D][0];
            float p = 0.f;
            int dd = h2 * 32;
#pragma unroll
            for (int i = 0; i < 8; ++i) {
                float4 xv = *(const float4*)(xrow + dd + i * 4);
                float4 wv = *(const float4*)(wrow + dd + i * 4);
                p += xv.x * wv.x + xv.y * wv.y + xv.z * wv.z + xv.w * wv.w;
            }
            p += __shfl_xor(p, 1);
            if (h2 == 0) skq[isq][l][D] = p;
        }
        __syncthreads();

        // ---- softmax over D -> k_h (with lr mult), q_h ----
        if (t < 32) {
            int isq = t >> 4, l = t & 15;
            float s0 = skq[isq][l][0], s1 = skq[isq][l][1];
            float s2 = skq[isq][l][2], s3 = skq[isq][l][3];
            float m = fmaxf(fmaxf(s0, s1), fmaxf(s2, s3));
            float e0 = expf(s0 - m), e1 = expf(s1 - m);
            float e2 = expf(s2 - m), e3 = expf(s3 - m);
            float inv = 1.f / (e0 + e1 + e2 + e3);
            if (isq == 0) {
                float mul = lrb[l][1] * inv;
                kh[l][0] = e0 * mul; kh[l][1] = e1 * mul;
                kh[l][2] = e2 * mul; kh[l][3] = e3 * mul;
            } else {
                qh[l][0] = e0 * inv; qh[l][1] = e1 * inv;
                qh[l][2] = e2 * inv; qh[l][3] = e3 * inv;
            }
        }
        __syncthreads();

        // ---- qk = (q_h . k_h^T) masked tril ----
        {
            int q = t >> 4, k = t & 15;
            float s = 0.f;
            if (k <= q) {
#pragma unroll
                for (int D = 0; D < 4; ++D) s += qh[q][D] * kh[k][D];
            }
            qkS[q][k] = s;
        }
        __syncthreads();

        // ---- o = q_h @ W_out + qk @ v ; fused LayerNorm + gate; write ----
        {
            int q = t >> 4;
            int d0 = d0q;
            float a0 = 0.f, a1 = 0.f, a2 = 0.f, a3 = 0.f;
#pragma unroll
            for (int D = 0; D < 4; ++D) {
                float qv = qh[q][D];
                float4 wv = *(const float4*)&Wo_[D][d0];
                a0 += qv * wv.x; a1 += qv * wv.y; a2 += qv * wv.z; a3 += qv * wv.w;
            }
#pragma unroll
            for (int k = 0; k < 16; ++k) {
                float s = qkS[q][k];
                float4 vv = *(const float4*)&sV[k][d0];
                a0 += s * vv.x; a1 += s * vv.y; a2 += s * vv.z; a3 += s * vv.w;
            }
            float sm = a0 + a1 + a2 + a3;
            float ss = a0 * a0 + a1 * a1 + a2 * a2 + a3 * a3;
#pragma unroll
            for (int m = 1; m <= 8; m <<= 1) {
                sm += __shfl_xor(sm, m);
                ss += __shfl_xor(ss, m);
            }
            float mu   = sm * (1.f / 64.f);
            float var  = ss * (1.f / 64.f) - mu * mu;
            float rstd = rsqrtf(var + 1e-5f);
            float4 g = *(const float4*)&GATE[(size_t)(rb + q) * DIM + h * 64 + d0];
            float4 o4;
            o4.x = ((a0 - mu) * rstd * lng4.x + lnb4.x) * g.x;
            o4.y = ((a1 - mu) * rstd * lng4.y + lnb4.y) * g.y;
            o4.z = ((a2 - mu) * rstd * lng4.z + lnb4.z) * g.z;
            o4.w = ((a3 - mu) * rstd * lng4.w + lnb4.w) * g.w;
            *(float4*)&OB[(size_t)(rb + q) * DIM + h * 64 + d0] = o4;
        }
        __syncthreads();

        // ---- W_out += k_h^T @ v ----
        {
            int D = t >> 6, d = t & 63;
            float s = 0.f;
#pragma unroll
            for (int k = 0; k < 16; ++k) s += kh[k][D] * sV[k][d];
            Wo_[D][d] += s;
        }
        __syncthreads();

        // ---- inner TTT loop (2 iters) ----
#pragma unroll 1
        for (int it = 0; it < 2; ++it) {
            // scores (pre-update W): a=0: W_in . k^T / 8 ; a=1: W_out . v^T / 8
            {
                int u = t >> 1, h2 = t & 1;
                int a = u >> 6;
                int rem = u & 63;
                int D = rem >> 4, j = rem & 15;
                const float* wrow = a ? &Wo_[D][0] : &Wi[D][0];
                const float* xrow = a ? &sV[j][0] : &sK[j][0];
                float p = 0.f;
                int dd = h2 * 32;
#pragma unroll
                for (int i = 0; i < 8; ++i) {
                    float4 xv = *(const float4*)(xrow + dd + i * 4);
                    float4 wv = *(const float4*)(wrow + dd + i * 4);
                    p += xv.x * wv.x + xv.y * wv.y + xv.z * wv.z + xv.w * wv.w;
                }
                p += __shfl_xor(p, 1);
                if (h2 == 0) sAtt[a][D][j] = p * 0.125f;
            }
            __syncthreads();

            // softmax over 16 keys
            if (t < 8) {
                int a = t >> 2, D = t & 3;
                float m = -1e30f;
#pragma unroll
                for (int j = 0; j < 16; ++j) m = fmaxf(m, sAtt[a][D][j]);
                float e[16];
                float sum = 0.f;
#pragma unroll
                for (int j = 0; j < 16; ++j) { e[j] = expf(sAtt[a][D][j] - m); sum += e[j]; }
                float inv = 1.f / sum;
#pragma unroll
                for (int j = 0; j < 16; ++j) pAtt[a][D][j] = e[j] * inv;
            }
            __syncthreads();

            // W_in += lr_in * (p1 @ k) ; W_out += lr_out * (p0 @ v)
            {
                int D = t >> 6, d = t & 63;
                float uo = 0.f, ui = 0.f;
#pragma unroll
                for (int j = 0; j < 16; ++j) {
                    uo += pAtt[0][D][j] * sV[j][d];
                    ui += pAtt[1][D][j] * sK[j][d];
                }
                Wi[D][d]  += lr_in * ui;
                Wo_[D][d] += lr_out * uo;
            }
            __syncthreads();
        }
    }
}

// ---------------------------------------------------------------------------
// launch
// ---------------------------------------------------------------------------
extern "C" void kernel_launch(void* const* d_in, const int* in_sizes, int n_in,
                              void* d_out, int out_size, void* d_ws, size_t ws_size,
                              hipStream_t stream)
{
    const float* hs  = (const float*)d_in[0];
    const float* Wq  = (const float*)d_in[1];
    const float* Wk  = (const float*)d_in[2];
    const float* Wv  = (const float*)d_in[3];
    const float* Wlr = (const float*)d_in[4];
    const float* Wg  = (const float*)d_in[5];
    const float* Wo  = (const float*)d_in[6];
    const float* cq  = (const float*)d_in[7];
    const float* ck  = (const float*)d_in[8];
    const float* cv  = (const float*)d_in[9];
    const float* Wi0 = (const float*)d_in[10];
    const float* Wo0 = (const float*)d_in[11];
    const float* lng = (const float*)d_in[12];
    const float* lnb = (const float*)d_in[13];

    // ws layout (floats), total ~203 MiB:
    //   Q    : 16384 x 1024   (proj q -> conv in place -> scan -> o_ln alias)
    //   K    : 16384 x 1024
    //   V    : 16384 x 1024
    //   LR   : 16384 x 32
    //   HALO : 3 * 4 * 64 * 3 * 1024
    // gate lives in d_out (consumed by scan before final GEMM overwrites).
    float* ws = (float*)d_ws;
    float* Q    = ws;
    float* K    = Q + (size_t)NROWS * DIM;
    float* V    = K + (size_t)NROWS * DIM;
    float* LRb  = V + (size_t)NROWS * DIM;
    float* HALO = LRb + (size_t)NROWS * 32;
    float* GATE = (float*)d_out;
    float* OBUF = Q;   // alias: scan reads its q slice before overwriting

    dim3 blk(256);

    // projections
    gemm_nt_f32<<<dim3(8, 128), blk, 0, stream>>>(hs, Wq, Q,    1024, DIM);
    gemm_nt_f32<<<dim3(8, 128), blk, 0, stream>>>(hs, Wk, K,    1024, DIM);
    gemm_nt_f32<<<dim3(8, 128), blk, 0, stream>>>(hs, Wv, V,    1024, DIM);
    gemm_nt_f32<<<dim3(8, 128), blk, 0, stream>>>(hs, Wg, GATE, 1024, DIM);

    // lr
    lr_kernel<<<NROWS, blk, 0, stream>>>(hs, Wlr, LRb);

    // halo save, then in-place conv + silu (+ l2norm q,k)
    halo_save<<<3 * BATCH * (NSEG - 1) * 3, blk, 0, stream>>>(Q, K, V, HALO);
    conv_inplace<<<(3 * BATCH * NH * NSEG) / 4, blk, 0, stream>>>(Q, K, V, HALO,
                                                                  cq, ck, cv);

    // sequential scan over chunks; fused LN + gate
    scan_kernel<<<BATCH * NH, blk, 0, stream>>>(Q, K, V, LRb, GATE,
                                                Wi0, Wo0, lng, lnb, OBUF);

    // out = (o_ln * gate) @ Wo^T
    gemm_nt_f32<<<dim3(8, 128), blk, 0, stream>>>(OBUF, Wo, (float*)d_out,
                                                  1024, 1024);
}

// Round 3
// 2817.135 us; speedup vs baseline: 1.3981x; 1.3981x over previous
//
#include <hip/hip_runtime.h>
#include <cstdint>
#include <cstddef>

// ---------------------------------------------------------------------------
// Sizes (fixed by the problem)
// ---------------------------------------------------------------------------
#define DIM    1024
#define NH     16
#define HD     64
#define DI     4
#define CHUNK_ 16
#define SEQ    4096
#define BATCH  4
#define NROWS  (BATCH * SEQ)       // 16384
#define NCHUNK (SEQ / CHUNK_)      // 256
#define SEG    64                  // conv in-place segment length (rows)
#define NSEG   (SEQ / SEG)         // 64

using bf16x8 = __attribute__((ext_vector_type(8))) short;
using f32x4  = __attribute__((ext_vector_type(4))) float;

__device__ __forceinline__ ushort f2bf(float f) {
    uint32_t u = __float_as_uint(f);
    u += 0x7FFFu + ((u >> 16) & 1u);      // RTNE
    return (ushort)(u >> 16);
}
__device__ __forceinline__ uint32_t pack2(float a, float b) {
    return (uint32_t)f2bf(a) | ((uint32_t)f2bf(b) << 16);
}
__device__ __forceinline__ float dot4(const float4 a, const float4 b) {
    return a.x*b.x + a.y*b.y + a.z*b.z + a.w*b.w;
}
__device__ __forceinline__ float4 fma4(float c, const float4 v, float4 a) {
    a.x = fmaf(c, v.x, a.x); a.y = fmaf(c, v.y, a.y);
    a.z = fmaf(c, v.z, a.z); a.w = fmaf(c, v.w, a.w);
    return a;
}

// ---------------------------------------------------------------------------
// bf16 MFMA GEMM (NT): C[m][n] = sum_k A[m*K+k] * B[n*K+k], fp32 in/out.
// 128x128 tile, BK=32, 4 waves, each wave 64x64 via 16 x mfma_16x16x32_bf16.
// LDS tiles [128][64] ushort with XOR block swizzle (16B block ^= row&7).
// ---------------------------------------------------------------------------
__global__ __launch_bounds__(256)
void gemm_nt_bf16(const float* __restrict__ A, const float* __restrict__ B,
                  float* __restrict__ C, int K, int ldc)
{
    __shared__ ushort As[128][64];
    __shared__ ushort Bs[128][64];

    const int tid  = threadIdx.x;
    const int m0   = blockIdx.y * 128, n0 = blockIdx.x * 128;
    const int wave = tid >> 6, lane = tid & 63;
    const int wm   = (wave >> 1) * 64, wn = (wave & 1) * 64;
    const int frow = lane & 15, fkg = lane >> 4;
    const int srow = tid >> 1, shalf = tid & 1;

    f32x4 acc[4][4];
#pragma unroll
    for (int i = 0; i < 4; ++i)
#pragma unroll
        for (int j = 0; j < 4; ++j) acc[i][j] = (f32x4){0.f, 0.f, 0.f, 0.f};

    const float* Ap0 = A + (size_t)(m0 + srow) * K + shalf * 16;
    const float* Bp0 = B + (size_t)(n0 + srow) * K + shalf * 16;
    const int swz0 = ((shalf * 2 + 0) ^ (srow & 7)) * 8;
    const int swz1 = ((shalf * 2 + 1) ^ (srow & 7)) * 8;
    const int rsw  = (frow & 7);

    for (int kt = 0; kt < K; kt += 32) {
        float4 a0 = *(const float4*)(Ap0 + kt);
        float4 a1 = *(const float4*)(Ap0 + kt + 4);
        float4 a2 = *(const float4*)(Ap0 + kt + 8);
        float4 a3 = *(const float4*)(Ap0 + kt + 12);
        float4 b0 = *(const float4*)(Bp0 + kt);
        float4 b1 = *(const float4*)(Bp0 + kt + 4);
        float4 b2 = *(const float4*)(Bp0 + kt + 8);
        float4 b3 = *(const float4*)(Bp0 + kt + 12);

        __syncthreads();
        uint4 u;
        u.x = pack2(a0.x, a0.y); u.y = pack2(a0.z, a0.w);
        u.z = pack2(a1.x, a1.y); u.w = pack2(a1.z, a1.w);
        *(uint4*)&As[srow][swz0] = u;
        u.x = pack2(a2.x, a2.y); u.y = pack2(a2.z, a2.w);
        u.z = pack2(a3.x, a3.y); u.w = pack2(a3.z, a3.w);
        *(uint4*)&As[srow][swz1] = u;
        u.x = pack2(b0.x, b0.y); u.y = pack2(b0.z, b0.w);
        u.z = pack2(b1.x, b1.y); u.w = pack2(b1.z, b1.w);
        *(uint4*)&Bs[srow][swz0] = u;
        u.x = pack2(b2.x, b2.y); u.y = pack2(b2.z, b2.w);
        u.z = pack2(b3.x, b3.y); u.w = pack2(b3.z, b3.w);
        *(uint4*)&Bs[srow][swz1] = u;
        __syncthreads();

        bf16x8 af[4], bf[4];
#pragma unroll
        for (int i = 0; i < 4; ++i) {
            af[i] = *(const bf16x8*)&As[wm + i * 16 + frow][(fkg ^ rsw) * 8];
            bf[i] = *(const bf16x8*)&Bs[wn + i * 16 + frow][(fkg ^ rsw) * 8];
        }
#pragma unroll
        for (int mt = 0; mt < 4; ++mt)
#pragma unroll
            for (int nt = 0; nt < 4; ++nt)
                acc[mt][nt] = __builtin_amdgcn_mfma_f32_16x16x32_bf16(
                    af[mt], bf[nt], acc[mt][nt], 0, 0, 0);
    }

    const int col = lane & 15, r4 = (lane >> 4) * 4;
#pragma unroll
    for (int mt = 0; mt < 4; ++mt)
#pragma unroll
        for (int nt = 0; nt < 4; ++nt)
#pragma unroll
            for (int j = 0; j < 4; ++j)
                C[(size_t)(m0 + wm + mt * 16 + r4 + j) * ldc +
                  (n0 + wn + nt * 16 + col)] = acc[mt][nt][j];
}

// ---------------------------------------------------------------------------
// lr kernel (exact fp32): LR[r][o] = softplus(hs[r,:].Wlr[o,:] + 1e-3)
// ---------------------------------------------------------------------------
__global__ __launch_bounds__(256)
void lr_kernel(const float* __restrict__ hs, const float* __restrict__ Wlr,
               float* __restrict__ LR)
{
    __shared__ float row[DIM];
    const int r = blockIdx.x;
    const int t = threadIdx.x;
    *(float4*)&row[t * 4] = *(const float4*)&hs[(size_t)r * DIM + t * 4];
    __syncthreads();

    const int o = t >> 3;
    const int p = t & 7;
    const float* w = Wlr + (size_t)o * DIM + p * 128;
    const float* x = row + p * 128;
    float acc = 0.f;
#pragma unroll
    for (int i = 0; i < 32; ++i) {
        float4 xv = *(const float4*)(x + i * 4);
        float4 wv = *(const float4*)(w + i * 4);
        acc += dot4(xv, wv);
    }
    acc += __shfl_xor(acc, 1);
    acc += __shfl_xor(acc, 2);
    acc += __shfl_xor(acc, 4);
    if (p == 0) {
        float xx = acc + 0.001f;
        LR[(size_t)r * 32 + o] = (xx > 20.f) ? xx : log1pf(expf(xx));
    }
}

// ---------------------------------------------------------------------------
// halo save (unchanged)
// ---------------------------------------------------------------------------
__global__ __launch_bounds__(256)
void halo_save(const float* __restrict__ Q, const float* __restrict__ K,
               const float* __restrict__ V, float* __restrict__ HALO)
{
    int idx = blockIdx.x;
    int tn  = idx / (BATCH * (NSEG - 1) * 3);
    int rem = idx - tn * (BATCH * (NSEG - 1) * 3);
    int b   = rem / ((NSEG - 1) * 3);
    int rem2= rem - b * ((NSEG - 1) * 3);
    int s   = rem2 / 3 + 1;
    int j   = rem2 - (s - 1) * 3;

    const float* buf = (tn == 0) ? Q : ((tn == 1) ? K : V);
    size_t src = ((size_t)(b * SEQ + s * SEG - 3 + j)) * DIM + threadIdx.x * 4;
    size_t dst = ((size_t)((tn * BATCH + b) * NSEG + s) * 3 + j) * DIM + threadIdx.x * 4;
    *(float4*)&HALO[dst] = *(const float4*)&buf[src];
}

// ---------------------------------------------------------------------------
// conv in-place (unchanged)
// ---------------------------------------------------------------------------
__global__ __launch_bounds__(256)
void conv_inplace(float* __restrict__ Q, float* __restrict__ K,
                  float* __restrict__ V, const float* __restrict__ HALO,
                  const float* __restrict__ cq, const float* __restrict__ ck,
                  const float* __restrict__ cv)
{
    const int wid  = (blockIdx.x << 2) + (threadIdx.x >> 6);
    const int lane = threadIdx.x & 63;
    const int tn   = wid >> 12;
    const int rem  = wid & 4095;
    const int b    = rem >> 10;
    const int rem2 = rem & 1023;
    const int h    = rem2 >> 6;
    const int s    = rem2 & 63;
    const int c    = (h << 6) + lane;

    float* buf = (tn == 0) ? Q : ((tn == 1) ? K : V);
    const float* cw = (tn == 0) ? cq : ((tn == 1) ? ck : cv);
    float4 w4 = *(const float4*)(cw + (c << 2));

    float xm3 = 0.f, xm2 = 0.f, xm1 = 0.f;
    if (s > 0) {
        size_t hb = ((size_t)((tn * BATCH + b) * NSEG + s) * 3) * DIM + c;
        xm3 = HALO[hb];
        xm2 = HALO[hb + DIM];
        xm1 = HALO[hb + 2 * DIM];
    }

    size_t base = ((size_t)(b * SEQ + s * SEG)) * DIM + c;
    float x_next = buf[base];
#pragma unroll 4
    for (int i = 0; i < SEG; ++i) {
        float x = x_next;
        if (i < SEG - 1) x_next = buf[base + (size_t)(i + 1) * DIM];
        float y = xm3 * w4.x + xm2 * w4.y + xm1 * w4.z + x * w4.w + x;
        y = y / (1.f + expf(-y));
        if (tn < 2) {
            float n2 = y * y;
#pragma unroll
            for (int m = 1; m < 64; m <<= 1) n2 += __shfl_xor(n2, m);
            y *= rsqrtf(n2);
        }
        buf[base + (size_t)i * DIM] = y;
        xm3 = xm2; xm2 = xm1; xm1 = x;
    }
}

// ---------------------------------------------------------------------------
// Scan kernel: ONE WAVE (64 threads) per (b,h) chain. Register-prefetched
// double buffer for next chunk; all phases use all 64 lanes; barriers are
// single-wave (cheap). Same math as the verified 256-thread version.
// Lane roles: (l = t>>2, D/dg = t&3) for logits/softmax/qk/o;
//             (D = t>>4, dg = t&15) for W updates.
// ---------------------------------------------------------------------------
__global__ __launch_bounds__(64)
void scan_kernel(const float* QP, const float* __restrict__ KP,
                 const float* __restrict__ VP, const float* __restrict__ LRb,
                 const float* __restrict__ GATE,
                 const float* __restrict__ Wi0, const float* __restrict__ Wo0,
                 const float* __restrict__ lng, const float* __restrict__ lnb,
                 float* OB)
{
    const int bh = blockIdx.x;
    const int b  = bh >> 4;
    const int h  = bh & 15;
    const int t  = threadIdx.x;

    __shared__ float sQ[16][68], sK[16][68], sV[16][68], sG[16][68];
    __shared__ float Wi[4][68], Wo_[4][68];
    __shared__ float khS[16][4], qhS[16][4];
    __shared__ float qkS[16][20];
    __shared__ float pA[2][4][20];

    const int uD = t >> 4, udg = t & 15;      // update-phase role
    const int o_q = t >> 2, o_dg = t & 3;     // logits/qk/o-phase role

    {   // init W state
        float4 wi4 = *(const float4*)&Wi0[((size_t)uD * NH + h) * HD + udg * 4];
        float4 wo4 = *(const float4*)&Wo0[((size_t)uD * NH + h) * HD + udg * 4];
        *(float4*)&Wi[uD][udg * 4]  = wi4;
        *(float4*)&Wo_[uD][udg * 4] = wo4;
    }
    float4 lngr[4], lnbr[4];
#pragma unroll
    for (int s = 0; s < 4; ++s) {
        lngr[s] = *(const float4*)&lng[o_dg * 16 + s * 4];
        lnbr[s] = *(const float4*)&lnb[o_dg * 16 + s * 4];
    }

    const int rowb = b * SEQ;
    const int pr = t >> 4, pd = (t & 15) * 4;     // prefetch/stage role

    float4 pq[4], pk[4], pv[4], pg[4];
    float plr = 0.f;

    // prefetch chunk 0
    {
        const int rb = rowb;
#pragma unroll
        for (int i = 0; i < 4; ++i) {
            size_t g = (size_t)(rb + i * 4 + pr) * DIM + h * 64 + pd;
            pq[i] = *(const float4*)&QP[g];
            pk[i] = *(const float4*)&KP[g];
            pv[i] = *(const float4*)&VP[g];
            pg[i] = *(const float4*)&GATE[g];
        }
        if (t < 32) plr = LRb[(size_t)(rb + (t >> 1)) * 32 + h * 2 + (t & 1)];
    }
    __syncthreads();

    for (int c = 0; c < NCHUNK; ++c) {
        const int rb = rowb + c * CHUNK_;

        // ---- stage from regs ----
#pragma unroll
        for (int i = 0; i < 4; ++i) {
            *(float4*)&sQ[i * 4 + pr][pd] = pq[i];
            *(float4*)&sK[i * 4 + pr][pd] = pk[i];
            *(float4*)&sV[i * 4 + pr][pd] = pv[i];
            *(float4*)&sG[i * 4 + pr][pd] = pg[i];
        }
        __syncthreads();

        const float lr1    = __shfl(plr, (o_q << 1) + 1);
        const float lr_in  = __shfl(plr, 0);
        const float lr_out = __shfl(plr, 1);

        // ---- prefetch next chunk ----
        if (c + 1 < NCHUNK) {
            const int rb2 = rb + CHUNK_;
#pragma unroll
            for (int i = 0; i < 4; ++i) {
                size_t g = (size_t)(rb2 + i * 4 + pr) * DIM + h * 64 + pd;
                pq[i] = *(const float4*)&QP[g];
                pk[i] = *(const float4*)&KP[g];
                pv[i] = *(const float4*)&VP[g];
                pg[i] = *(const float4*)&GATE[g];
            }
            if (t < 32) plr = LRb[(size_t)(rb2 + (t >> 1)) * 32 + h * 2 + (t & 1)];
        }

        // ---- logits: s[l,D] = {k,q}[l,:].Wi[D,:] ----
        float sk = 0.f, sq = 0.f;
#pragma unroll
        for (int dd = 0; dd < 16; ++dd) {
            float4 wv = *(const float4*)&Wi[o_dg][dd * 4];
            float4 kv = *(const float4*)&sK[o_q][dd * 4];
            float4 qv = *(const float4*)&sQ[o_q][dd * 4];
            sk += dot4(kv, wv);
            sq += dot4(qv, wv);
        }

        // ---- softmax over D (4-lane group) ----
        {
            float m = fmaxf(sk, __shfl_xor(sk, 1));
            m = fmaxf(m, __shfl_xor(m, 2));
            float e = expf(sk - m);
            float su = e + __shfl_xor(e, 1);
            su += __shfl_xor(su, 2);
            khS[o_q][o_dg] = (e / su) * lr1;

            float mq = fmaxf(sq, __shfl_xor(sq, 1));
            mq = fmaxf(mq, __shfl_xor(mq, 2));
            float eq = expf(sq - mq);
            float sz = eq + __shfl_xor(eq, 1);
            sz += __shfl_xor(sz, 2);
            qhS[o_q][o_dg] = eq / sz;
        }
        __syncthreads();

        // ---- qk (tril): lane (q, kg) computes 4 entries ----
        {
            float4 qrow = *(const float4*)&qhS[o_q][0];
            float out[4];
#pragma unroll
            for (int j = 0; j < 4; ++j) {
                int k = o_dg * 4 + j;
                float4 kr = *(const float4*)&khS[k][0];
                float s = dot4(qrow, kr);
                out[j] = (k <= o_q) ? s : 0.f;
            }
            *(float4*)&qkS[o_q][o_dg * 4] =
                make_float4(out[0], out[1], out[2], out[3]);
        }
        __syncthreads();

        // ---- o = qh@Wo + qk@v ; LN + gate ; write ----
        {
            float4 acc[4] = {{0,0,0,0},{0,0,0,0},{0,0,0,0},{0,0,0,0}};
            float4 qrow = *(const float4*)&qhS[o_q][0];
            float qarr[4] = {qrow.x, qrow.y, qrow.z, qrow.w};
#pragma unroll
            for (int D = 0; D < 4; ++D) {
                float cf = qarr[D];
#pragma unroll
                for (int s = 0; s < 4; ++s)
                    acc[s] = fma4(cf, *(const float4*)&Wo_[D][o_dg * 16 + s * 4], acc[s]);
            }
#pragma unroll
            for (int k = 0; k < 16; ++k) {
                float sc = qkS[o_q][k];
#pragma unroll
                for (int s = 0; s < 4; ++s)
                    acc[s] = fma4(sc, *(const float4*)&sV[k][o_dg * 16 + s * 4], acc[s]);
            }
            float sm = 0.f, ss = 0.f;
#pragma unroll
            for (int s = 0; s < 4; ++s) {
                sm += acc[s].x + acc[s].y + acc[s].z + acc[s].w;
                ss += acc[s].x * acc[s].x + acc[s].y * acc[s].y +
                      acc[s].z * acc[s].z + acc[s].w * acc[s].w;
            }
            sm += __shfl_xor(sm, 1); sm += __shfl_xor(sm, 2);
            ss += __shfl_xor(ss, 1); ss += __shfl_xor(ss, 2);
            float mu   = sm * (1.f / 64.f);
            float var  = ss * (1.f / 64.f) - mu * mu;
            float rstd = rsqrtf(var + 1e-5f);
#pragma unroll
            for (int s = 0; s < 4; ++s) {
                float4 g4 = *(const float4*)&sG[o_q][o_dg * 16 + s * 4];
                float4 o4;
                o4.x = ((acc[s].x - mu) * rstd * lngr[s].x + lnbr[s].x) * g4.x;
                o4.y = ((acc[s].y - mu) * rstd * lngr[s].y + lnbr[s].y) * g4.y;
                o4.z = ((acc[s].z - mu) * rstd * lngr[s].z + lnbr[s].z) * g4.z;
                o4.w = ((acc[s].w - mu) * rstd * lngr[s].w + lnbr[s].w) * g4.w;
                *(float4*)&OB[(size_t)(rb + o_q) * DIM + h * 64 + o_dg * 16 + s * 4] = o4;
            }
        }
        __syncthreads();   // o's reads of Wo_ complete

        // ---- W_out += kh^T @ v ----
        {
            float4 a = *(const float4*)&Wo_[uD][udg * 4];
#pragma unroll
            for (int k = 0; k < 16; ++k)
                a = fma4(khS[k][uD], *(const float4*)&sV[k][udg * 4], a);
            *(float4*)&Wo_[uD][udg * 4] = a;
        }
        __syncthreads();

        // ---- inner TTT loop (2 iters) ----
#pragma unroll 1
        for (int it = 0; it < 2; ++it) {
            // scores: lane (j = o_q, D = o_dg); both attns at once
            float s0 = 0.f, s1 = 0.f;
#pragma unroll
            for (int dd = 0; dd < 16; ++dd) {
                float4 wiv = *(const float4*)&Wi[o_dg][dd * 4];
                float4 wov = *(const float4*)&Wo_[o_dg][dd * 4];
                float4 kv  = *(const float4*)&sK[o_q][dd * 4];
                float4 vv  = *(const float4*)&sV[o_q][dd * 4];
                s0 += dot4(wiv, kv);
                s1 += dot4(wov, vv);
            }
            s0 *= 0.125f; s1 *= 0.125f;

            // softmax over j (lanes stride 4): xor 4,8,16,32
            float m0 = s0, m1 = s1;
#pragma unroll
            for (int msk = 4; msk <= 32; msk <<= 1) {
                m0 = fmaxf(m0, __shfl_xor(m0, msk));
                m1 = fmaxf(m1, __shfl_xor(m1, msk));
            }
            float e0 = expf(s0 - m0), e1 = expf(s1 - m1);
            float su0 = e0, su1 = e1;
#pragma unroll
            for (int msk = 4; msk <= 32; msk <<= 1) {
                su0 += __shfl_xor(su0, msk);
                su1 += __shfl_xor(su1, msk);
            }
            pA[0][o_dg][o_q] = e0 / su0;   // attn(W_in, k, v) probs
            pA[1][o_dg][o_q] = e1 / su1;   // attn(W_out, v, k) probs
            __syncthreads();

            // W_in += lr_in * p1 @ k ; W_out += lr_out * p0 @ v
            {
                float4 wiA = *(const float4*)&Wi[uD][udg * 4];
                float4 woA = *(const float4*)&Wo_[uD][udg * 4];
#pragma unroll
                for (int j = 0; j < 16; ++j) {
                    float p0v = pA[0][uD][j];
                    float p1v = pA[1][uD][j];
                    wiA = fma4(lr_in * p1v, *(const float4*)&sK[j][udg * 4], wiA);
                    woA = fma4(lr_out * p0v, *(const float4*)&sV[j][udg * 4], woA);
                }
                *(float4*)&Wi[uD][udg * 4]  = wiA;
                *(float4*)&Wo_[uD][udg * 4] = woA;
            }
            __syncthreads();
        }
    }
}

// ---------------------------------------------------------------------------
// launch
// ---------------------------------------------------------------------------
extern "C" void kernel_launch(void* const* d_in, const int* in_sizes, int n_in,
                              void* d_out, int out_size, void* d_ws, size_t ws_size,
                              hipStream_t stream)
{
    const float* hs  = (const float*)d_in[0];
    const float* Wq  = (const float*)d_in[1];
    const float* Wk  = (const float*)d_in[2];
    const float* Wv  = (const float*)d_in[3];
    const float* Wlr = (const float*)d_in[4];
    const float* Wg  = (const float*)d_in[5];
    const float* Wo  = (const float*)d_in[6];
    const float* cq  = (const float*)d_in[7];
    const float* ck  = (const float*)d_in[8];
    const float* cv  = (const float*)d_in[9];
    const float* Wi0 = (const float*)d_in[10];
    const float* Wo0 = (const float*)d_in[11];
    const float* lng = (const float*)d_in[12];
    const float* lnb = (const float*)d_in[13];

    float* ws = (float*)d_ws;
    float* Q    = ws;
    float* K    = Q + (size_t)NROWS * DIM;
    float* V    = K + (size_t)NROWS * DIM;
    float* LRb  = V + (size_t)NROWS * DIM;
    float* HALO = LRb + (size_t)NROWS * 32;
    float* GATE = (float*)d_out;
    float* OBUF = Q;

    dim3 blk(256);

    gemm_nt_bf16<<<dim3(8, 128), blk, 0, stream>>>(hs, Wq, Q,    1024, DIM);
    gemm_nt_bf16<<<dim3(8, 128), blk, 0, stream>>>(hs, Wk, K,    1024, DIM);
    gemm_nt_bf16<<<dim3(8, 128), blk, 0, stream>>>(hs, Wv, V,    1024, DIM);
    gemm_nt_bf16<<<dim3(8, 128), blk, 0, stream>>>(hs, Wg, GATE, 1024, DIM);

    lr_kernel<<<NROWS, blk, 0, stream>>>(hs, Wlr, LRb);

    halo_save<<<3 * BATCH * (NSEG - 1) * 3, blk, 0, stream>>>(Q, K, V, HALO);
    conv_inplace<<<(3 * BATCH * NH * NSEG) / 4, blk, 0, stream>>>(Q, K, V, HALO,
                                                                  cq, ck, cv);

    scan_kernel<<<BATCH * NH, dim3(64), 0, stream>>>(Q, K, V, LRb, GATE,
                                                     Wi0, Wo0, lng, lnb, OBUF);

    gemm_nt_bf16<<<dim3(8, 128), blk, 0, stream>>>(OBUF, Wo, (float*)d_out,
                                                   1024, 1024);
}

// Round 4
// 2747.090 us; speedup vs baseline: 1.4337x; 1.0255x over previous
//
#include <hip/hip_runtime.h>
#include <cstdint>
#include <cstddef>

// ---------------------------------------------------------------------------
// Sizes (fixed by the problem)
// ---------------------------------------------------------------------------
#define DIM    1024
#define NH     16
#define HD     64
#define DI     4
#define CHUNK_ 16
#define SEQ    4096
#define BATCH  4
#define NROWS  (BATCH * SEQ)       // 16384
#define NCHUNK (SEQ / CHUNK_)      // 256
#define SEG    64                  // conv in-place segment length (rows)
#define NSEG   (SEQ / SEG)         // 64

using bf16x8 = __attribute__((ext_vector_type(8))) short;
using f32x4  = __attribute__((ext_vector_type(4))) float;

typedef union { bf16x8 v; uint32_t u[4]; } B8;

__device__ __forceinline__ ushort f2bf(float f) {
    uint32_t u = __float_as_uint(f);
    u += 0x7FFFu + ((u >> 16) & 1u);      // RTNE
    return (ushort)(u >> 16);
}
__device__ __forceinline__ uint32_t pack2(float a, float b) {
    return (uint32_t)f2bf(a) | ((uint32_t)f2bf(b) << 16);
}
__device__ __forceinline__ float dot4(const float4 a, const float4 b) {
    return a.x*b.x + a.y*b.y + a.z*b.z + a.w*b.w;
}
__device__ __forceinline__ float redmax16(float x) {
    x = fmaxf(x, __shfl_xor(x, 1)); x = fmaxf(x, __shfl_xor(x, 2));
    x = fmaxf(x, __shfl_xor(x, 4)); x = fmaxf(x, __shfl_xor(x, 8));
    return x;
}
__device__ __forceinline__ float redsum16(float x) {
    x += __shfl_xor(x, 1); x += __shfl_xor(x, 2);
    x += __shfl_xor(x, 4); x += __shfl_xor(x, 8);
    return x;
}

// ---------------------------------------------------------------------------
// bf16 MFMA GEMM (NT): C[m][n] = sum_k A[m*K+k] * B[n*K+k], fp32 in/out.
// (unchanged from round 3 — verified)
// ---------------------------------------------------------------------------
__global__ __launch_bounds__(256)
void gemm_nt_bf16(const float* __restrict__ A, const float* __restrict__ B,
                  float* __restrict__ C, int K, int ldc)
{
    __shared__ ushort As[128][64];
    __shared__ ushort Bs[128][64];

    const int tid  = threadIdx.x;
    const int m0   = blockIdx.y * 128, n0 = blockIdx.x * 128;
    const int wave = tid >> 6, lane = tid & 63;
    const int wm   = (wave >> 1) * 64, wn = (wave & 1) * 64;
    const int frow = lane & 15, fkg = lane >> 4;
    const int srow = tid >> 1, shalf = tid & 1;

    f32x4 acc[4][4];
#pragma unroll
    for (int i = 0; i < 4; ++i)
#pragma unroll
        for (int j = 0; j < 4; ++j) acc[i][j] = (f32x4){0.f, 0.f, 0.f, 0.f};

    const float* Ap0 = A + (size_t)(m0 + srow) * K + shalf * 16;
    const float* Bp0 = B + (size_t)(n0 + srow) * K + shalf * 16;
    const int swz0 = ((shalf * 2 + 0) ^ (srow & 7)) * 8;
    const int swz1 = ((shalf * 2 + 1) ^ (srow & 7)) * 8;
    const int rsw  = (frow & 7);

    for (int kt = 0; kt < K; kt += 32) {
        float4 a0 = *(const float4*)(Ap0 + kt);
        float4 a1 = *(const float4*)(Ap0 + kt + 4);
        float4 a2 = *(const float4*)(Ap0 + kt + 8);
        float4 a3 = *(const float4*)(Ap0 + kt + 12);
        float4 b0 = *(const float4*)(Bp0 + kt);
        float4 b1 = *(const float4*)(Bp0 + kt + 4);
        float4 b2 = *(const float4*)(Bp0 + kt + 8);
        float4 b3 = *(const float4*)(Bp0 + kt + 12);

        __syncthreads();
        uint4 u;
        u.x = pack2(a0.x, a0.y); u.y = pack2(a0.z, a0.w);
        u.z = pack2(a1.x, a1.y); u.w = pack2(a1.z, a1.w);
        *(uint4*)&As[srow][swz0] = u;
        u.x = pack2(a2.x, a2.y); u.y = pack2(a2.z, a2.w);
        u.z = pack2(a3.x, a3.y); u.w = pack2(a3.z, a3.w);
        *(uint4*)&As[srow][swz1] = u;
        u.x = pack2(b0.x, b0.y); u.y = pack2(b0.z, b0.w);
        u.z = pack2(b1.x, b1.y); u.w = pack2(b1.z, b1.w);
        *(uint4*)&Bs[srow][swz0] = u;
        u.x = pack2(b2.x, b2.y); u.y = pack2(b2.z, b2.w);
        u.z = pack2(b3.x, b3.y); u.w = pack2(b3.z, b3.w);
        *(uint4*)&Bs[srow][swz1] = u;
        __syncthreads();

        bf16x8 af[4], bf[4];
#pragma unroll
        for (int i = 0; i < 4; ++i) {
            af[i] = *(const bf16x8*)&As[wm + i * 16 + frow][(fkg ^ rsw) * 8];
            bf[i] = *(const bf16x8*)&Bs[wn + i * 16 + frow][(fkg ^ rsw) * 8];
        }
#pragma unroll
        for (int mt = 0; mt < 4; ++mt)
#pragma unroll
            for (int nt = 0; nt < 4; ++nt)
                acc[mt][nt] = __builtin_amdgcn_mfma_f32_16x16x32_bf16(
                    af[mt], bf[nt], acc[mt][nt], 0, 0, 0);
    }

    const int col = lane & 15, r4 = (lane >> 4) * 4;
#pragma unroll
    for (int mt = 0; mt < 4; ++mt)
#pragma unroll
        for (int nt = 0; nt < 4; ++nt)
#pragma unroll
            for (int j = 0; j < 4; ++j)
                C[(size_t)(m0 + wm + mt * 16 + r4 + j) * ldc +
                  (n0 + wn + nt * 16 + col)] = acc[mt][nt][j];
}

// ---------------------------------------------------------------------------
// lr kernel (exact fp32)
// ---------------------------------------------------------------------------
__global__ __launch_bounds__(256)
void lr_kernel(const float* __restrict__ hs, const float* __restrict__ Wlr,
               float* __restrict__ LR)
{
    __shared__ float row[DIM];
    const int r = blockIdx.x;
    const int t = threadIdx.x;
    *(float4*)&row[t * 4] = *(const float4*)&hs[(size_t)r * DIM + t * 4];
    __syncthreads();

    const int o = t >> 3;
    const int p = t & 7;
    const float* w = Wlr + (size_t)o * DIM + p * 128;
    const float* x = row + p * 128;
    float acc = 0.f;
#pragma unroll
    for (int i = 0; i < 32; ++i) {
        float4 xv = *(const float4*)(x + i * 4);
        float4 wv = *(const float4*)(w + i * 4);
        acc += dot4(xv, wv);
    }
    acc += __shfl_xor(acc, 1);
    acc += __shfl_xor(acc, 2);
    acc += __shfl_xor(acc, 4);
    if (p == 0) {
        float xx = acc + 0.001f;
        LR[(size_t)r * 32 + o] = (xx > 20.f) ? xx : log1pf(expf(xx));
    }
}

// ---------------------------------------------------------------------------
// halo save (unchanged)
// ---------------------------------------------------------------------------
__global__ __launch_bounds__(256)
void halo_save(const float* __restrict__ Q, const float* __restrict__ K,
               const float* __restrict__ V, float* __restrict__ HALO)
{
    int idx = blockIdx.x;
    int tn  = idx / (BATCH * (NSEG - 1) * 3);
    int rem = idx - tn * (BATCH * (NSEG - 1) * 3);
    int b   = rem / ((NSEG - 1) * 3);
    int rem2= rem - b * ((NSEG - 1) * 3);
    int s   = rem2 / 3 + 1;
    int j   = rem2 - (s - 1) * 3;

    const float* buf = (tn == 0) ? Q : ((tn == 1) ? K : V);
    size_t src = ((size_t)(b * SEQ + s * SEG - 3 + j)) * DIM + threadIdx.x * 4;
    size_t dst = ((size_t)((tn * BATCH + b) * NSEG + s) * 3 + j) * DIM + threadIdx.x * 4;
    *(float4*)&HALO[dst] = *(const float4*)&buf[src];
}

// ---------------------------------------------------------------------------
// conv in-place (unchanged)
// ---------------------------------------------------------------------------
__global__ __launch_bounds__(256)
void conv_inplace(float* __restrict__ Q, float* __restrict__ K,
                  float* __restrict__ V, const float* __restrict__ HALO,
                  const float* __restrict__ cq, const float* __restrict__ ck,
                  const float* __restrict__ cv)
{
    const int wid  = (blockIdx.x << 2) + (threadIdx.x >> 6);
    const int lane = threadIdx.x & 63;
    const int tn   = wid >> 12;
    const int rem  = wid & 4095;
    const int b    = rem >> 10;
    const int rem2 = rem & 1023;
    const int h    = rem2 >> 6;
    const int s    = rem2 & 63;
    const int c    = (h << 6) + lane;

    float* buf = (tn == 0) ? Q : ((tn == 1) ? K : V);
    const float* cw = (tn == 0) ? cq : ((tn == 1) ? ck : cv);
    float4 w4 = *(const float4*)(cw + (c << 2));

    float xm3 = 0.f, xm2 = 0.f, xm1 = 0.f;
    if (s > 0) {
        size_t hb = ((size_t)((tn * BATCH + b) * NSEG + s) * 3) * DIM + c;
        xm3 = HALO[hb];
        xm2 = HALO[hb + DIM];
        xm1 = HALO[hb + 2 * DIM];
    }

    size_t base = ((size_t)(b * SEQ + s * SEG)) * DIM + c;
    float x_next = buf[base];
#pragma unroll 4
    for (int i = 0; i < SEG; ++i) {
        float x = x_next;
        if (i < SEG - 1) x_next = buf[base + (size_t)(i + 1) * DIM];
        float y = xm3 * w4.x + xm2 * w4.y + xm1 * w4.z + x * w4.w + x;
        y = y / (1.f + expf(-y));
        if (tn < 2) {
            float n2 = y * y;
#pragma unroll
            for (int m = 1; m < 64; m <<= 1) n2 += __shfl_xor(n2, m);
            y *= rsqrtf(n2);
        }
        buf[base + (size_t)i * DIM] = y;
        xm3 = xm2; xm2 = xm1; xm1 = x;
    }
}

// ---------------------------------------------------------------------------
// MFMA scan: ONE WAVE per (b,h) chain. All matmul phases on matrix cores
// (mfma_f32_16x16x32_bf16); W_in/W_out masters fp32 in C-layout registers;
// bf16 shadows in LDS refreshed after each update.
//
// mfma semantics (HW-verified by the GEMM above):
//   D[xr][yr] = sum_k X[xr][k]*Y[yr][k]
//   X/Y frag: xr/yr = lane&15, k = (lane>>4)*8 + j   (bf16x8, j=0..7)
//   C/D frag: col(yr) = lane&15, row(xr) = (lane>>4)*4 + reg
// ---------------------------------------------------------------------------
__global__ __launch_bounds__(64)
void scan_kernel(const float* QP, const float* __restrict__ KP,
                 const float* __restrict__ VP, const float* __restrict__ LRb,
                 const float* __restrict__ GATE,
                 const float* __restrict__ Wi0, const float* __restrict__ Wo0,
                 const float* __restrict__ lng, const float* __restrict__ lnb,
                 float* OB)
{
    const int bh = blockIdx.x, b = bh >> 4, h = bh & 15;
    const int t  = threadIdx.x, lo = t & 15, g = t >> 4;

    // row-major bf16 operand tiles (row stride padded for bank spread)
    __shared__ ushort KA[16][72], QA[16][72], VA[16][72];   // K/Q/V rows [l][d]
    __shared__ ushort KT[64][24];                           // K^T  [d][l] (cols 16-23 zero)
    __shared__ ushort VT[64][40];                           // [d][ 0-15: V^T | 16-19: Wo^T | 20-39: zero ]
    __shared__ ushort WiA[16][72], WoA[16][72];             // W rows [D][d], rows 4-15 zero
    __shared__ ushort QKT[16][32];                          // [q][ 0-15: qk | 16-19: q_h | 20-31: zero ]
    __shared__ ushort P0s[16][32], P1s[16][32], KH[16][32]; // rows 4-15 & cols 16-31 zero
    __shared__ float  sG[16][68];

    // ---- zero-once regions ----
    for (int i = t; i < 16 * 72; i += 64) { ((ushort*)WiA)[i] = 0; ((ushort*)WoA)[i] = 0; }
    for (int i = t; i < 64 * 24; i += 64) ((ushort*)KT)[i] = 0;
    for (int i = t; i < 64 * 40; i += 64) ((ushort*)VT)[i] = 0;
    for (int i = t; i < 16 * 32; i += 64) {
        ((ushort*)QKT)[i] = 0; ((ushort*)P0s)[i] = 0;
        ((ushort*)P1s)[i] = 0; ((ushort*)KH)[i]  = 0;
    }

    // ---- W masters (fp32, C-layout: lanes 0-15 hold Wi[D][16n+lo]) ----
    f32x4 wiC[4], woC[4];
#pragma unroll
    for (int n = 0; n < 4; ++n) { wiC[n] = (f32x4){0,0,0,0}; woC[n] = (f32x4){0,0,0,0}; }
    if (g == 0) {
#pragma unroll
        for (int n = 0; n < 4; ++n)
#pragma unroll
            for (int D = 0; D < 4; ++D) {
                float wi = Wi0[((size_t)D * NH + h) * HD + 16 * n + lo];
                float wo = Wo0[((size_t)D * NH + h) * HD + 16 * n + lo];
                wiC[n][D] = wi; woC[n][D] = wo;
                WiA[D][16 * n + lo] = f2bf(wi);
                WoA[D][16 * n + lo] = f2bf(wo);
                VT[16 * n + lo][16 + D] = f2bf(wo);
            }
    }
    __syncthreads();

    float lnGr[4], lnBr[4];
#pragma unroll
    for (int n = 0; n < 4; ++n) { lnGr[n] = lng[16 * n + lo]; lnBr[n] = lnb[16 * n + lo]; }

    const int rowb = b * SEQ;
    float4 pq[4], pk[4], pv[4], pg[4];
    float plr = 0.f;
    {   // prefetch chunk 0
#pragma unroll
        for (int i = 0; i < 4; ++i) {
            size_t go = (size_t)(rowb + i * 4 + g) * DIM + h * 64 + 4 * lo;
            pq[i] = *(const float4*)&QP[go];
            pk[i] = *(const float4*)&KP[go];
            pv[i] = *(const float4*)&VP[go];
            pg[i] = *(const float4*)&GATE[go];
        }
        if (t < 32) plr = LRb[(size_t)(rowb + (t >> 1)) * 32 + h * 2 + (t & 1)];
    }

    const f32x4 z4 = (f32x4){0.f, 0.f, 0.f, 0.f};

    for (int c = 0; c < NCHUNK; ++c) {
        const int rb = rowb + c * CHUNK_;

        // ---- stage chunk (regs -> LDS, bf16 + transposed copies) ----
#pragma unroll
        for (int i = 0; i < 4; ++i) {
            const int row = i * 4 + g;
            *(float4*)&sG[row][4 * lo] = pg[i];
            uint2 uq; uq.x = pack2(pq[i].x, pq[i].y); uq.y = pack2(pq[i].z, pq[i].w);
            *(uint2*)&QA[row][4 * lo] = uq;
            uint2 uk; uk.x = pack2(pk[i].x, pk[i].y); uk.y = pack2(pk[i].z, pk[i].w);
            *(uint2*)&KA[row][4 * lo] = uk;
            uint2 uv; uv.x = pack2(pv[i].x, pv[i].y); uv.y = pack2(pv[i].z, pv[i].w);
            *(uint2*)&VA[row][4 * lo] = uv;
            KT[4 * lo + 0][row] = (ushort)(uk.x & 0xFFFF);
            KT[4 * lo + 1][row] = (ushort)(uk.x >> 16);
            KT[4 * lo + 2][row] = (ushort)(uk.y & 0xFFFF);
            KT[4 * lo + 3][row] = (ushort)(uk.y >> 16);
            VT[4 * lo + 0][row] = (ushort)(uv.x & 0xFFFF);
            VT[4 * lo + 1][row] = (ushort)(uv.x >> 16);
            VT[4 * lo + 2][row] = (ushort)(uv.y & 0xFFFF);
            VT[4 * lo + 3][row] = (ushort)(uv.y >> 16);
        }
        const float lr1    = __shfl(plr, 2 * lo + 1);
        const float lr_in  = __shfl(plr, 0);
        const float lr_out = __shfl(plr, 1);

        // ---- prefetch next chunk ----
        if (c + 1 < NCHUNK) {
            const int rb2 = rb + CHUNK_;
#pragma unroll
            for (int i = 0; i < 4; ++i) {
                size_t go = (size_t)(rb2 + i * 4 + g) * DIM + h * 64 + 4 * lo;
                pq[i] = *(const float4*)&QP[go];
                pk[i] = *(const float4*)&KP[go];
                pv[i] = *(const float4*)&VP[go];
                pg[i] = *(const float4*)&GATE[go];
            }
            if (t < 32) plr = LRb[(size_t)(rb2 + (t >> 1)) * 32 + h * 2 + (t & 1)];
        }
        __syncthreads();

        // ---- M1/M2: logits^T  cK[D][l], cQ[D][l]  (valid on lanes 0-15) ----
        bf16x8 xWi0 = *(const bf16x8*)&WiA[lo][g * 8];
        bf16x8 xWi1 = *(const bf16x8*)&WiA[lo][g * 8 + 32];
        f32x4 cK = __builtin_amdgcn_mfma_f32_16x16x32_bf16(
            xWi0, *(const bf16x8*)&KA[lo][g * 8], z4, 0, 0, 0);
        cK = __builtin_amdgcn_mfma_f32_16x16x32_bf16(
            xWi1, *(const bf16x8*)&KA[lo][g * 8 + 32], cK, 0, 0, 0);
        f32x4 cQ = __builtin_amdgcn_mfma_f32_16x16x32_bf16(
            xWi0, *(const bf16x8*)&QA[lo][g * 8], z4, 0, 0, 0);
        cQ = __builtin_amdgcn_mfma_f32_16x16x32_bf16(
            xWi1, *(const bf16x8*)&QA[lo][g * 8 + 32], cQ, 0, 0, 0);

        // ---- softmax over D: register-local (lane lo = row l) ----
        float mK = fmaxf(fmaxf(cK[0], cK[1]), fmaxf(cK[2], cK[3]));
        float ek0 = expf(cK[0] - mK), ek1 = expf(cK[1] - mK);
        float ek2 = expf(cK[2] - mK), ek3 = expf(cK[3] - mK);
        float ivk = lr1 / (ek0 + ek1 + ek2 + ek3);
        float kh0 = ek0 * ivk, kh1 = ek1 * ivk, kh2 = ek2 * ivk, kh3 = ek3 * ivk;

        float mQ = fmaxf(fmaxf(cQ[0], cQ[1]), fmaxf(cQ[2], cQ[3]));
        float eq0 = expf(cQ[0] - mQ), eq1 = expf(cQ[1] - mQ);
        float eq2 = expf(cQ[2] - mQ), eq3 = expf(cQ[3] - mQ);
        float ivq = 1.f / (eq0 + eq1 + eq2 + eq3);
        float qh0 = eq0 * ivq, qh1 = eq1 * ivq, qh2 = eq2 * ivq, qh3 = eq3 * ivq;

        // ---- M3: qk = q_h @ k_h^T  (pure-register mfma) ----
        B8 aQh, bKh;
        aQh.u[0] = aQh.u[1] = aQh.u[2] = aQh.u[3] = 0;
        bKh.u[0] = bKh.u[1] = bKh.u[2] = bKh.u[3] = 0;
        if (g == 0) {
            aQh.u[0] = pack2(qh0, qh1); aQh.u[1] = pack2(qh2, qh3);
            bKh.u[0] = pack2(kh0, kh1); bKh.u[1] = pack2(kh2, kh3);
        }
        f32x4 cQK = __builtin_amdgcn_mfma_f32_16x16x32_bf16(aQh.v, bKh.v, z4, 0, 0, 0);

        // ---- bounce qk (tril-masked) + q_h into QKT ----
#pragma unroll
        for (int r = 0; r < 4; ++r) {
            const int q = 4 * g + r;
            QKT[q][lo] = (lo <= q) ? f2bf(cQK[r]) : (ushort)0;
        }
        if (g == 0) {
            QKT[lo][16] = f2bf(qh0); QKT[lo][17] = f2bf(qh1);
            QKT[lo][18] = f2bf(qh2); QKT[lo][19] = f2bf(qh3);
        }
        __syncthreads();

        // ---- M4: o = qk_ext @ [V | Wo]  (4 tiles over d) ----
        bf16x8 aO = *(const bf16x8*)&QKT[lo][g * 8];
        f32x4 oA[4];
#pragma unroll
        for (int n = 0; n < 4; ++n)
            oA[n] = __builtin_amdgcn_mfma_f32_16x16x32_bf16(
                aO, *(const bf16x8*)&VT[16 * n + lo][g * 8], z4, 0, 0, 0);

        // ---- LN + gate + store (q = 4g+reg, d = 16n+lo) ----
#pragma unroll
        for (int r = 0; r < 4; ++r) {
            float s1 = oA[0][r] + oA[1][r] + oA[2][r] + oA[3][r];
            float s2 = oA[0][r] * oA[0][r] + oA[1][r] * oA[1][r] +
                       oA[2][r] * oA[2][r] + oA[3][r] * oA[3][r];
            s1 = redsum16(s1); s2 = redsum16(s2);
            float mu = s1 * (1.f / 64.f);
            float rstd = rsqrtf(s2 * (1.f / 64.f) - mu * mu + 1e-5f);
            const int q = 4 * g + r;
#pragma unroll
            for (int n = 0; n < 4; ++n) {
                float val = (oA[n][r] - mu) * rstd * lnGr[n] + lnBr[n];
                val *= sG[q][16 * n + lo];
                OB[(size_t)(rb + q) * DIM + h * 64 + 16 * n + lo] = val;
            }
        }

        // ---- update1: W_out += k_h^T @ V ----
        if (g == 0) {
            KH[0][lo] = f2bf(kh0); KH[1][lo] = f2bf(kh1);
            KH[2][lo] = f2bf(kh2); KH[3][lo] = f2bf(kh3);
        }
        __syncthreads();
        {
            bf16x8 aKH = *(const bf16x8*)&KH[lo][g * 8];
#pragma unroll
            for (int n = 0; n < 4; ++n)
                woC[n] = __builtin_amdgcn_mfma_f32_16x16x32_bf16(
                    aKH, *(const bf16x8*)&VT[16 * n + lo][g * 8], woC[n], 0, 0, 0);
        }
        if (g == 0) {
#pragma unroll
            for (int n = 0; n < 4; ++n)
#pragma unroll
                for (int D = 0; D < 4; ++D)
                    WoA[D][16 * n + lo] = f2bf(woC[n][D]);
        }
        __syncthreads();

        // ---- inner TTT loop (2 iters) ----
#pragma unroll
        for (int it = 0; it < 2; ++it) {
            f32x4 s0v;
            if (it == 0) {
                s0v = cK;                      // logits reuse (Wi unchanged)
            } else {
                bf16x8 yWi0 = *(const bf16x8*)&WiA[lo][g * 8];
                bf16x8 yWi1 = *(const bf16x8*)&WiA[lo][g * 8 + 32];
                s0v = __builtin_amdgcn_mfma_f32_16x16x32_bf16(
                    yWi0, *(const bf16x8*)&KA[lo][g * 8], z4, 0, 0, 0);
                s0v = __builtin_amdgcn_mfma_f32_16x16x32_bf16(
                    yWi1, *(const bf16x8*)&KA[lo][g * 8 + 32], s0v, 0, 0, 0);
            }
            bf16x8 yWo0 = *(const bf16x8*)&WoA[lo][g * 8];
            bf16x8 yWo1 = *(const bf16x8*)&WoA[lo][g * 8 + 32];
            f32x4 s1v = __builtin_amdgcn_mfma_f32_16x16x32_bf16(
                yWo0, *(const bf16x8*)&VA[lo][g * 8], z4, 0, 0, 0);
            s1v = __builtin_amdgcn_mfma_f32_16x16x32_bf16(
                yWo1, *(const bf16x8*)&VA[lo][g * 8 + 32], s1v, 0, 0, 0);

            // softmax over j (16 lanes; valid on lanes 0-15)
            float p0v[4], p1v[4];
#pragma unroll
            for (int r = 0; r < 4; ++r) {
                float x0 = s0v[r] * 0.125f, x1 = s1v[r] * 0.125f;
                float m0 = redmax16(x0), m1 = redmax16(x1);
                float e0 = expf(x0 - m0), e1 = expf(x1 - m1);
                p0v[r] = e0 / redsum16(e0);
                p1v[r] = e1 / redsum16(e1);
            }
            if (g == 0) {
#pragma unroll
                for (int r = 0; r < 4; ++r) {
                    P0s[r][lo] = f2bf(p0v[r] * lr_out);
                    P1s[r][lo] = f2bf(p1v[r] * lr_in);
                }
            }
            __syncthreads();

            bf16x8 aP0 = *(const bf16x8*)&P0s[lo][g * 8];
            bf16x8 aP1 = *(const bf16x8*)&P1s[lo][g * 8];
#pragma unroll
            for (int n = 0; n < 4; ++n) {
                woC[n] = __builtin_amdgcn_mfma_f32_16x16x32_bf16(
                    aP0, *(const bf16x8*)&VT[16 * n + lo][g * 8], woC[n], 0, 0, 0);
                wiC[n] = __builtin_amdgcn_mfma_f32_16x16x32_bf16(
                    aP1, *(const bf16x8*)&KT[16 * n + lo][g * 8], wiC[n], 0, 0, 0);
            }
            if (g == 0) {
#pragma unroll
                for (int n = 0; n < 4; ++n)
#pragma unroll
                    for (int D = 0; D < 4; ++D) {
                        WiA[D][16 * n + lo] = f2bf(wiC[n][D]);
                        WoA[D][16 * n + lo] = f2bf(woC[n][D]);
                        if (it == 1) VT[16 * n + lo][16 + D] = f2bf(woC[n][D]);
                    }
            }
            __syncthreads();
        }
    }
}

// ---------------------------------------------------------------------------
// launch
// ---------------------------------------------------------------------------
extern "C" void kernel_launch(void* const* d_in, const int* in_sizes, int n_in,
                              void* d_out, int out_size, void* d_ws, size_t ws_size,
                              hipStream_t stream)
{
    const float* hs  = (const float*)d_in[0];
    const float* Wq  = (const float*)d_in[1];
    const float* Wk  = (const float*)d_in[2];
    const float* Wv  = (const float*)d_in[3];
    const float* Wlr = (const float*)d_in[4];
    const float* Wg  = (const float*)d_in[5];
    const float* Wo  = (const float*)d_in[6];
    const float* cq  = (const float*)d_in[7];
    const float* ck  = (const float*)d_in[8];
    const float* cv  = (const float*)d_in[9];
    const float* Wi0 = (const float*)d_in[10];
    const float* Wo0 = (const float*)d_in[11];
    const float* lng = (const float*)d_in[12];
    const float* lnb = (const float*)d_in[13];

    float* ws = (float*)d_ws;
    float* Q    = ws;
    float* K    = Q + (size_t)NROWS * DIM;
    float* V    = K + (size_t)NROWS * DIM;
    float* LRb  = V + (size_t)NROWS * DIM;
    float* HALO = LRb + (size_t)NROWS * 32;
    float* GATE = (float*)d_out;
    float* OBUF = Q;

    dim3 blk(256);

    gemm_nt_bf16<<<dim3(8, 128), blk, 0, stream>>>(hs, Wq, Q,    1024, DIM);
    gemm_nt_bf16<<<dim3(8, 128), blk, 0, stream>>>(hs, Wk, K,    1024, DIM);
    gemm_nt_bf16<<<dim3(8, 128), blk, 0, stream>>>(hs, Wv, V,    1024, DIM);
    gemm_nt_bf16<<<dim3(8, 128), blk, 0, stream>>>(hs, Wg, GATE, 1024, DIM);

    lr_kernel<<<NROWS, blk, 0, stream>>>(hs, Wlr, LRb);

    halo_save<<<3 * BATCH * (NSEG - 1) * 3, blk, 0, stream>>>(Q, K, V, HALO);
    conv_inplace<<<(3 * BATCH * NH * NSEG) / 4, blk, 0, stream>>>(Q, K, V, HALO,
                                                                  cq, ck, cv);

    scan_kernel<<<BATCH * NH, dim3(64), 0, stream>>>(Q, K, V, LRb, GATE,
                                                     Wi0, Wo0, lng, lnb, OBUF);

    gemm_nt_bf16<<<dim3(8, 128), blk, 0, stream>>>(OBUF, Wo, (float*)d_out,
                                                   1024, 1024);
}